// Round 8
// baseline (100.272 us; speedup 1.0000x reference)
//
#include <hip/hip_runtime.h>
#include <hip/hip_bf16.h>

// B=16, N=2048, DIM_X=512, DIM_E=64, F=576 (=512+64)
// out_b = Xe_b * (Wbig * (Xe_b^T x_b)) -- three NT-GEMMs, no NxN matrix.
// Stage 1 is a Gram (syrk): compute block-lower triangle only + mirror.

typedef __attribute__((ext_vector_type(8))) short s16x8;
typedef __attribute__((ext_vector_type(4))) short s16x4;
typedef __attribute__((ext_vector_type(4))) float f32x4;

__device__ __forceinline__ unsigned short f2bf(float f) {
  union { float f; unsigned u; } v; v.f = f;
  unsigned r = v.u + 0x7fff + ((v.u >> 16) & 1);   // RNE
  return (unsigned short)(r >> 16);
}

// ---------------------------------------------------------------------------
// NT-GEMM: C[i][j] = sum_k A[i][k]*B[j][k]. bf16 in, f32 acc, bf16/f32 out.
// TMxTN tile, TK=64, 256 threads = 4 waves (2x2). Proven round-3/4 loop:
// global_load_lds w16 staging, 2-buffer LDS, prefetch-before-compute, ONE
// __syncthreads per K-tile. LDS swizzle both-sides (16B slot ^= row&7) via
// pre-swizzled global source. XCD batch grouping.
// TRI: tile grid is the block-lower triangle of a GX*TM square (TM==TN).
// KSW>=0: A-source for k-tiles t>=KSW switches to batch-shared A2 (lda2).
// ---------------------------------------------------------------------------
template<int TM, int TN, int GX, int GY, int OUT_F32, int TRI, int KSW>
__global__ __launch_bounds__(256) void gemm_nt(
    const unsigned short* __restrict__ A, long sAb, int lda,
    const unsigned short* __restrict__ A2, int lda2,
    const unsigned short* __restrict__ B, long sBb, int ldb,
    void* __restrict__ Cptr, long sCb, int ldc,
    int K)
{
  constexpr int TK = 64;
  constexpr int WM = TM / 2, WN = TN / 2;
  constexpr int AM = WM / 16, AN = WN / 16;
  constexpr int ACH = TM / 8;
  constexpr int BCH = TN / 8;
  constexpr int NBLK = TRI ? (GX * (GX + 1)) / 2 : GX * GY;

  __shared__ unsigned short As[2][TM * TK];
  __shared__ unsigned short Bs[2][TN * TK];

  const int bid  = blockIdx.x;
  const int xcd  = bid & 7;
  const int slot = bid >> 3;
  const int bz   = xcd + 8 * (slot / NBLK);
  const int tix  = slot % NBLK;
  int m0, n0;
  if (TRI) {
    int ti = 0, rem = tix;
    while (rem >= ti + 1) { rem -= ti + 1; ++ti; }
    m0 = ti * TM; n0 = rem * TN;
  } else {
    m0 = (tix % GX) * TM; n0 = (tix / GX) * TN;
  }

  const unsigned short* Ab = A + (long)bz * sAb;
  const unsigned short* Bb = B + (long)bz * sBb;

  const int tid  = threadIdx.x;
  const int lane = tid & 63;
  const int wave = tid >> 6;
  const int wm = (wave >> 1) * WM;
  const int wn = (wave & 1) * WN;
  const int fr = lane & 15;
  const int fg = lane >> 4;
  const int fx = fr & 7;

  const int srow = lane >> 3;
  const int scol = (((lane & 7) ^ (lane >> 3)) & 7) * 8;  // pre-swizzled src col

  f32x4 acc[AM][AN];
#pragma unroll
  for (int i = 0; i < AM; i++)
#pragma unroll
    for (int j = 0; j < AN; j++) acc[i][j] = (f32x4)(0.f);

  auto stage = [&](int buf, int t) {
    const int k0 = t * TK;
    const unsigned short* asrc;
    int asl;
    if (KSW >= 0 && t >= KSW) { asrc = A2 + (k0 - KSW * TK); asl = lda2; }
    else                      { asrc = Ab + k0;              asl = lda;  }
#pragma unroll
    for (int i = 0; i < ACH / 4; i++) {
      const int c = wave * (ACH / 4) + i;
      __builtin_amdgcn_global_load_lds(
          (const __attribute__((address_space(1))) unsigned*)
              (asrc + (long)(m0 + c * 8 + srow) * asl + scol),
          (__attribute__((address_space(3))) unsigned*)(&As[buf][c * 512]),
          16, 0, 0);
    }
#pragma unroll
    for (int i = 0; i < BCH / 4; i++) {
      const int c = wave * (BCH / 4) + i;
      __builtin_amdgcn_global_load_lds(
          (const __attribute__((address_space(1))) unsigned*)
              (Bb + (long)(n0 + c * 8 + srow) * ldb + k0 + scol),
          (__attribute__((address_space(3))) unsigned*)(&Bs[buf][c * 512]),
          16, 0, 0);
    }
  };

  const int NT = K / TK;
  stage(0, 0);
  __syncthreads();

  for (int t = 0; t < NT; ++t) {
    const int cur = t & 1;
    if (t + 1 < NT) stage(cur ^ 1, t + 1);

    const unsigned short* Ac = &As[cur][0];
    const unsigned short* Bc = &Bs[cur][0];
#pragma unroll
    for (int ks = 0; ks < 2; ks++) {
      s16x8 av[AM], bv[AN];
#pragma unroll
      for (int mt = 0; mt < AM; mt++)
        av[mt] = *(const s16x8*)
            &Ac[(wm + mt * 16 + fr) * TK + (((ks * 4 + fg) ^ fx) * 8)];
#pragma unroll
      for (int nt = 0; nt < AN; nt++)
        bv[nt] = *(const s16x8*)
            &Bc[(wn + nt * 16 + fr) * TK + (((ks * 4 + fg) ^ fx) * 8)];
#pragma unroll
      for (int mt = 0; mt < AM; mt++)
#pragma unroll
        for (int nt = 0; nt < AN; nt++)
          acc[mt][nt] = __builtin_amdgcn_mfma_f32_16x16x32_bf16(
              av[mt], bv[nt], acc[mt][nt], 0, 0, 0);
    }
    __syncthreads();
  }

  // D layout (verified m89): col = lane&15, row = (lane>>4)*4 + j
  if (OUT_F32) {
    float* C = (float*)Cptr + (long)bz * sCb;
#pragma unroll
    for (int mt = 0; mt < AM; mt++) {
      const int row = m0 + wm + mt * 16 + fg * 4;
#pragma unroll
      for (int nt = 0; nt < AN; nt++) {
        const int col = n0 + wn + nt * 16 + fr;
#pragma unroll
        for (int j = 0; j < 4; j++)
          C[(long)(row + j) * ldc + col] = acc[mt][nt][j];
      }
    }
  } else {
    unsigned short* C = (unsigned short*)Cptr + (long)bz * sCb;
#pragma unroll
    for (int mt = 0; mt < AM; mt++) {
      const int row = m0 + wm + mt * 16 + fg * 4;
#pragma unroll
      for (int nt = 0; nt < AN; nt++) {
        const int col = n0 + wn + nt * 16 + fr;
#pragma unroll
        for (int j = 0; j < 4; j++)
          C[(long)(row + j) * ldc + col] = f2bf(acc[mt][nt][j]);
      }
    }
  }
}

// ---------------------------------------------------------------------------
// mirror: fill strict upper triangle of G[b] (576x576 bf16) rows < 512 from
// the computed block-lower triangle: G[i][j] = G[j][i] for j > i.
// 32x32 LDS-transpose tiles; grid (16, 18, 16), skip jt < it.
// ---------------------------------------------------------------------------
__global__ __launch_bounds__(256) void mirror_g(unsigned short* __restrict__ G)
{
  const int it = blockIdx.x;            // i-tile: rows 0..511
  const int jt = blockIdx.y;            // j-tile: cols 0..575
  if (jt < it) return;
  const long S = (long)576 * 576;
  unsigned short* Gb = G + (long)blockIdx.z * S;
  const int i0 = it * 32, j0 = jt * 32;
  const int r  = threadIdx.x >> 3;        // 0..31
  const int c4 = (threadIdx.x & 7) * 4;   // 0..28

  __shared__ unsigned short t[32][36];
  // read lower: row j0+r, cols i0+c4.. (coalesced 64B runs)
  s16x4 v = *(const s16x4*)&Gb[(long)(j0 + r) * 576 + i0 + c4];
#pragma unroll
  for (int q = 0; q < 4; ++q) t[r][c4 + q] = v[q];
  __syncthreads();

  // write upper: row i0+r, cols j0+c4.. ; value = G[j][i] = t[col][r]
  if (it == jt) {
#pragma unroll
    for (int q = 0; q < 4; ++q) {
      const int j = j0 + c4 + q, i = i0 + r;
      if (j > i) Gb[(long)i * 576 + j] = t[c4 + q][r];
    }
  } else {
    s16x4 o;
#pragma unroll
    for (int q = 0; q < 4; ++q) o[q] = t[c4 + q][r];
    *(s16x4*)&Gb[(long)(i0 + r) * 576 + j0 + c4] = o;
  }
}

// ---------------------------------------------------------------------------
// convert_x: register-transpose, no LDS. Each thread owns an 8x8 block of
// x[b]; writes Xb rows (straight bf16 cast, 256B runs) and XeT columns.
// ---------------------------------------------------------------------------
__global__ __launch_bounds__(256) void convert_x(
    const float* __restrict__ x,
    unsigned short* __restrict__ XeT, unsigned short* __restrict__ Xb)
{
  const int b  = blockIdx.z;
  const int k0 = blockIdx.x * 128;
  const int f0 = blockIdx.y * 128;
  const int lane = threadIdx.x & 63;
  const int w    = threadIdx.x >> 6;
  const int fg = lane & 15;            // 16 f-octets -> 128 f
  const int kg = w * 4 + (lane >> 4);  // 16 k-octets -> 128 k
  const int kk = k0 + kg * 8;
  const int ff = f0 + fg * 8;

  unsigned short h[8][8];
#pragma unroll
  for (int j = 0; j < 8; ++j) {
    const float* src = &x[((long)b * 2048 + kk + j) * 512 + ff];
    float4 a = *(const float4*)src;
    float4 c = *(const float4*)(src + 4);
    h[j][0] = f2bf(a.x); h[j][1] = f2bf(a.y);
    h[j][2] = f2bf(a.z); h[j][3] = f2bf(a.w);
    h[j][4] = f2bf(c.x); h[j][5] = f2bf(c.y);
    h[j][6] = f2bf(c.z); h[j][7] = f2bf(c.w);
  }
#pragma unroll
  for (int j = 0; j < 8; ++j) {
    s16x8 o;
#pragma unroll
    for (int q = 0; q < 8; ++q) o[q] = h[j][q];
    *(s16x8*)&Xb[((long)b * 2048 + kk + j) * 512 + ff] = o;
  }
#pragma unroll
  for (int r = 0; r < 8; ++r) {
    s16x8 o;
#pragma unroll
    for (int q = 0; q < 8; ++q) o[q] = h[q][r];
    *(s16x8*)&XeT[((long)b * 576 + ff + r) * 2048 + kk] = o;
  }
}

// convert_e: e[2048][64] -> XeT[b][512+f][k] for all b; eb[n][f] once (b==0).
__global__ __launch_bounds__(256) void convert_e(
    const float* __restrict__ e,
    unsigned short* __restrict__ XeT, unsigned short* __restrict__ eb)
{
  const int b  = blockIdx.y;
  const int k0 = blockIdx.x * 256;
  const int lane = threadIdx.x & 63;
  const int w    = threadIdx.x >> 6;
  const int fg = lane & 7;             // 8 f-octets -> 64 f
  const int kg = w * 8 + (lane >> 3);  // 32 k-octets -> 256 k
  const int kk = k0 + kg * 8;
  const int ff = fg * 8;

  unsigned short h[8][8];
#pragma unroll
  for (int j = 0; j < 8; ++j) {
    const float* src = &e[(long)(kk + j) * 64 + ff];
    float4 a = *(const float4*)src;
    float4 c = *(const float4*)(src + 4);
    h[j][0] = f2bf(a.x); h[j][1] = f2bf(a.y);
    h[j][2] = f2bf(a.z); h[j][3] = f2bf(a.w);
    h[j][4] = f2bf(c.x); h[j][5] = f2bf(c.y);
    h[j][6] = f2bf(c.z); h[j][7] = f2bf(c.w);
  }
  if (b == 0) {
#pragma unroll
    for (int j = 0; j < 8; ++j) {
      s16x8 o;
#pragma unroll
      for (int q = 0; q < 8; ++q) o[q] = h[j][q];
      *(s16x8*)&eb[(long)(kk + j) * 64 + ff] = o;
    }
  }
#pragma unroll
  for (int r = 0; r < 8; ++r) {
    s16x8 o;
#pragma unroll
    for (int q = 0; q < 8; ++q) o[q] = h[q][r];
    *(s16x8*)&XeT[((long)b * 576 + 512 + ff + r) * 2048 + kk] = o;
  }
}

// ---------------------------------------------------------------------------
// Wb[m][k] (576x576 bf16) = quadrant-wise transpose of W0..W3 with
// relu(triu) on the W0 block. 32x32 LDS tiles; coalesced reads AND writes.
// ---------------------------------------------------------------------------
__global__ __launch_bounds__(256) void build_wb(
    const float* __restrict__ W0, const float* __restrict__ W1,
    const float* __restrict__ W2, const float* __restrict__ W3,
    unsigned short* __restrict__ Wb)
{
  __shared__ float tw[32][33];
  const int m0 = blockIdx.x * 32;
  const int k0 = blockIdx.y * 32;
  const int r  = threadIdx.x >> 3;        // 0..31
  const int c4 = (threadIdx.x & 7) * 4;   // 0..28

  const int k = k0 + r;
  float4 v;
  if (m0 < 512) {
    if (k0 < 512) v = *(const float4*)&W0[k * 512 + m0 + c4];
    else          v = *(const float4*)&W1[(k - 512) * 512 + m0 + c4];
  } else {
    if (k0 < 512) v = *(const float4*)&W2[k * 64 + (m0 - 512) + c4];
    else          v = *(const float4*)&W3[(k - 512) * 64 + (m0 - 512) + c4];
  }
  tw[r][c4 + 0] = v.x; tw[r][c4 + 1] = v.y; tw[r][c4 + 2] = v.z; tw[r][c4 + 3] = v.w;
  __syncthreads();

  const int m = m0 + r;
  const bool tri = (m0 < 512) && (k0 < 512);
  s16x4 o;
#pragma unroll
  for (int j = 0; j < 4; ++j) {
    const int kk = k0 + c4 + j;
    float val = tw[c4 + j][r];
    if (tri) val = (m > kk) ? fmaxf(val, 0.f) : 0.f;
    o[j] = f2bf(val);
  }
  *(s16x4*)&Wb[m * 576 + k0 + c4] = o;
}

// ---------------------------------------------------------------------------
extern "C" void kernel_launch(void* const* d_in, const int* in_sizes, int n_in,
                              void* d_out, int out_size, void* d_ws, size_t ws_size,
                              hipStream_t stream) {
  const float* x  = (const float*)d_in[0];
  const float* e  = (const float*)d_in[1];
  const float* W0 = (const float*)d_in[2];
  const float* W1 = (const float*)d_in[3];
  const float* W2 = (const float*)d_in[4];
  const float* W3 = (const float*)d_in[5];
  float* out = (float*)d_out;

  const size_t SZ_XeT = (size_t)16 * 576 * 2048 * 2;  // 37,748,736
  const size_t SZ_G   = (size_t)16 * 576 * 576 * 2;   // 10,616,832
  const size_t SZ_DT  = (size_t)16 * 512 * 576 * 2;   //  9,437,184
  const size_t SZ_WB  = (size_t)576 * 576 * 2;        //    663,552
  const size_t SZ_XB  = (size_t)16 * 2048 * 512 * 2;  // 33,554,432
  const size_t SZ_EB  = (size_t)2048 * 64 * 2;        //    262,144

  char* p = (char*)d_ws;
  unsigned short* XeT = (unsigned short*)p;  p += SZ_XeT;
  unsigned short* G   = (unsigned short*)p;  p += SZ_G;
  unsigned short* DT  = (unsigned short*)p;  p += SZ_DT;
  unsigned short* Wb  = (unsigned short*)p;  p += SZ_WB;
  unsigned short* Xb  = (unsigned short*)p;  p += SZ_XB;
  unsigned short* eb  = (unsigned short*)p;  p += SZ_EB;
  const size_t base = SZ_XeT + SZ_G + SZ_DT + SZ_WB + SZ_XB + SZ_EB;
  if (ws_size < base) return;  // d_ws is 256MiB; loud failure otherwise

  build_wb<<<dim3(18, 18), 256, 0, stream>>>(W0, W1, W2, W3, Wb);
  convert_x<<<dim3(16, 4, 16), 256, 0, stream>>>(x, XeT, Xb);
  convert_e<<<dim3(8, 16), 256, 0, stream>>>(e, XeT, eb);

  // Stage 1 (syrk, block-lower triangle): G[i][j] = sum_k XeT[i][k]*XeT[j][k]
  // 45 triangle tiles of 64x64 over 576x576; 720 blocks = 2.8/CU.
  gemm_nt<64, 64, 9, 0, 0, 1, -1><<<720, 256, 0, stream>>>(
      XeT, (long)576 * 2048, 2048, nullptr, 0,
      XeT, (long)576 * 2048, 2048,
      G,   (long)576 * 576, 576, 2048);

  mirror_g<<<dim3(16, 18, 16), 256, 0, stream>>>(G);

  // Stage 2: DT[t][m] = sum_f G[t][f]*Wb[m][f]     (M=512, N=576, K=576)
  gemm_nt<64, 96, 8, 6, 0, 0, -1><<<768, 256, 0, stream>>>(
      G,  (long)576 * 576, 576, nullptr, 0,
      Wb, 0L, 576,
      DT, (long)512 * 576, 576, 576);

  // Stage 3: out[n][t] = sum_m A[n][m]*DT[t][m]    (M=2048, N=512, K=576)
  // A: k<512 from Xb (per-batch), k-tile 8 from batch-shared eb.
  gemm_nt<128, 128, 16, 4, 1, 0, 8><<<1024, 256, 0, stream>>>(
      Xb, (long)2048 * 512, 512, eb, 64,
      DT, (long)512 * 576, 576,
      out, (long)2048 * 512, 512, 576);
}

// Round 9
// 89.073 us; speedup vs baseline: 1.1257x; 1.1257x over previous
//
#include <hip/hip_runtime.h>
#include <hip/hip_bf16.h>

// B=16, N=2048, DIM_X=512, DIM_E=64, F=576 (=512+64)
// out_b = Xe_b * (Wbig * (Xe_b^T x_b))  -- three NT-GEMMs, no NxN matrix.
// Champion config (round 4, 94.0us) + build_wb folded into convert_fused.

typedef __attribute__((ext_vector_type(8))) short s16x8;
typedef __attribute__((ext_vector_type(4))) short s16x4;
typedef __attribute__((ext_vector_type(4))) float f32x4;

__device__ __forceinline__ unsigned short f2bf(float f) {
  union { float f; unsigned u; } v; v.f = f;
  unsigned r = v.u + 0x7fff + ((v.u >> 16) & 1);   // RNE
  return (unsigned short)(r >> 16);
}

// ---------------------------------------------------------------------------
// NT-GEMM: C[i][j] = sum_k A[i][k]*B[j][k]. A: MxK, B: NxK row-major bf16;
// C: MxN (bf16 or f32). TMxTN tile, TK=64, 256 threads = 4 waves (2x2).
// global_load_lds w16 staging, 2-buffer LDS, prefetch-before-compute, ONE
// __syncthreads per K-tile (vmcnt(0) drain = the wait; counted-vmcnt
// REGRESSED in this 2-phase structure -- round 5, m141, m230). LDS swizzle
// both-sides (16B slot ^= row&7) via pre-swizzled global source. XCD batch
// grouping (bid&7 -> batches {x, x+8}). Grids must be ~exact multiples of
// 256 CUs (rounds 6/8: per-CU block-count quantization dominates).
// ---------------------------------------------------------------------------
template<int TM, int TN, int GX, int GY, int OUT_F32>
__global__ __launch_bounds__(256) void gemm_nt(
    const unsigned short* __restrict__ A, long sAb, int lda,
    const unsigned short* __restrict__ B, long sBb, int ldb,
    void* __restrict__ Cptr, long sCb, int ldc,
    int K)
{
  constexpr int TK = 64;
  constexpr int WM = TM / 2, WN = TN / 2;
  constexpr int AM = WM / 16, AN = WN / 16;
  constexpr int ACH = TM / 8;
  constexpr int BCH = TN / 8;
  constexpr int NBLK = GX * GY;

  __shared__ unsigned short As[2][TM * TK];
  __shared__ unsigned short Bs[2][TN * TK];

  const int bid  = blockIdx.x;
  const int xcd  = bid & 7;
  const int slot = bid >> 3;
  const int bz   = xcd + 8 * (slot / NBLK);
  const int tix  = slot % NBLK;
  const int m0   = (tix % GX) * TM;
  const int n0   = (tix / GX) * TN;

  const unsigned short* Ab = A + (long)bz * sAb;
  const unsigned short* Bb = B + (long)bz * sBb;

  const int tid  = threadIdx.x;
  const int lane = tid & 63;
  const int wave = tid >> 6;
  const int wm = (wave >> 1) * WM;
  const int wn = (wave & 1) * WN;
  const int fr = lane & 15;
  const int fg = lane >> 4;
  const int fx = fr & 7;

  const int srow = lane >> 3;
  const int scol = (((lane & 7) ^ (lane >> 3)) & 7) * 8;  // pre-swizzled src col

  f32x4 acc[AM][AN];
#pragma unroll
  for (int i = 0; i < AM; i++)
#pragma unroll
    for (int j = 0; j < AN; j++) acc[i][j] = (f32x4)(0.f);

  auto stage = [&](int buf, int k0) {
#pragma unroll
    for (int i = 0; i < ACH / 4; i++) {
      const int c = wave * (ACH / 4) + i;
      __builtin_amdgcn_global_load_lds(
          (const __attribute__((address_space(1))) unsigned*)
              (Ab + (long)(m0 + c * 8 + srow) * lda + k0 + scol),
          (__attribute__((address_space(3))) unsigned*)(&As[buf][c * 512]),
          16, 0, 0);
    }
#pragma unroll
    for (int i = 0; i < BCH / 4; i++) {
      const int c = wave * (BCH / 4) + i;
      __builtin_amdgcn_global_load_lds(
          (const __attribute__((address_space(1))) unsigned*)
              (Bb + (long)(n0 + c * 8 + srow) * ldb + k0 + scol),
          (__attribute__((address_space(3))) unsigned*)(&Bs[buf][c * 512]),
          16, 0, 0);
    }
  };

  const int NT = K / TK;
  stage(0, 0);
  __syncthreads();

  for (int t = 0; t < NT; ++t) {
    const int cur = t & 1;
    if (t + 1 < NT) stage(cur ^ 1, (t + 1) * TK);

    const unsigned short* Ac = &As[cur][0];
    const unsigned short* Bc = &Bs[cur][0];
#pragma unroll
    for (int ks = 0; ks < 2; ks++) {
      s16x8 av[AM], bv[AN];
#pragma unroll
      for (int mt = 0; mt < AM; mt++)
        av[mt] = *(const s16x8*)
            &Ac[(wm + mt * 16 + fr) * TK + (((ks * 4 + fg) ^ fx) * 8)];
#pragma unroll
      for (int nt = 0; nt < AN; nt++)
        bv[nt] = *(const s16x8*)
            &Bc[(wn + nt * 16 + fr) * TK + (((ks * 4 + fg) ^ fx) * 8)];
#pragma unroll
      for (int mt = 0; mt < AM; mt++)
#pragma unroll
        for (int nt = 0; nt < AN; nt++)
          acc[mt][nt] = __builtin_amdgcn_mfma_f32_16x16x32_bf16(
              av[mt], bv[nt], acc[mt][nt], 0, 0, 0);
    }
    __syncthreads();
  }

  // D layout (verified m89): col = lane&15, row = (lane>>4)*4 + j
  if (OUT_F32) {
    float* C = (float*)Cptr + (long)bz * sCb;
#pragma unroll
    for (int mt = 0; mt < AM; mt++) {
      const int row = m0 + wm + mt * 16 + fg * 4;
#pragma unroll
      for (int nt = 0; nt < AN; nt++) {
        const int col = n0 + wn + nt * 16 + fr;
#pragma unroll
        for (int j = 0; j < 4; j++)
          C[(long)(row + j) * ldc + col] = acc[mt][nt][j];
      }
    }
  } else {
    unsigned short* C = (unsigned short*)Cptr + (long)bz * sCb;
#pragma unroll
    for (int mt = 0; mt < AM; mt++) {
      const int row = m0 + wm + mt * 16 + fg * 4;
#pragma unroll
      for (int nt = 0; nt < AN; nt++) {
        const int col = n0 + wn + nt * 16 + fr;
#pragma unroll
        for (int j = 0; j < 4; j++)
          C[(long)(row + j) * ldc + col] = f2bf(acc[mt][nt][j]);
      }
    }
  }
}

// ---------------------------------------------------------------------------
// convert_fused (+Wb): z<16: per 64x64 tile of batch z, read x/e (f32),
// write Xe (bf16, straight) from registers and XeT (bf16, transposed) via an
// LDS tile (pad=2 -> 132B stride). z in {16,17}: build Wb[m][k] (576x576
// bf16) = quadrant-wise transpose of W0..W3 with relu(striu) on W0 block,
// 32x32 LDS-transpose tiles (324 tiles mapped onto the y*32+x block space).
// ---------------------------------------------------------------------------
__global__ __launch_bounds__(256) void convert_fused(
    const float* __restrict__ x, const float* __restrict__ e,
    const float* __restrict__ W0, const float* __restrict__ W1,
    const float* __restrict__ W2, const float* __restrict__ W3,
    unsigned short* __restrict__ XeT, unsigned short* __restrict__ Xe,
    unsigned short* __restrict__ Wb)
{
  constexpr int LP = 66;             // row stride in elems (64 + 2 pad)
  __shared__ unsigned short t[64 * LP];   // 8448B; Wb path reuses 4224B as f32

  if (blockIdx.z >= 16) {
    // ---- Wb tile path ----
    const int tidx = (blockIdx.z - 16) * 288 + blockIdx.y * 32 + blockIdx.x;
    if (tidx >= 324) return;
    float* tw = (float*)t;                  // [32][33]
    const int m0 = (tidx / 18) * 32;
    const int k0 = (tidx % 18) * 32;
    const int r  = threadIdx.x >> 3;        // 0..31
    const int c4 = (threadIdx.x & 7) * 4;   // 0..28

    const int k = k0 + r;
    float4 v;
    if (m0 < 512) {
      if (k0 < 512) v = *(const float4*)&W0[k * 512 + m0 + c4];
      else          v = *(const float4*)&W1[(k - 512) * 512 + m0 + c4];
    } else {
      if (k0 < 512) v = *(const float4*)&W2[k * 64 + (m0 - 512) + c4];
      else          v = *(const float4*)&W3[(k - 512) * 64 + (m0 - 512) + c4];
    }
    tw[r * 33 + c4 + 0] = v.x; tw[r * 33 + c4 + 1] = v.y;
    tw[r * 33 + c4 + 2] = v.z; tw[r * 33 + c4 + 3] = v.w;
    __syncthreads();

    const int m = m0 + r;
    const bool tri = (m0 < 512) && (k0 < 512);
    s16x4 o;
#pragma unroll
    for (int j = 0; j < 4; ++j) {
      const int kk = k0 + c4 + j;
      float val = tw[(c4 + j) * 33 + r];
      if (tri) val = (m > kk) ? fmaxf(val, 0.f) : 0.f;
      o[j] = f2bf(val);
    }
    *(s16x4*)&Wb[m * 576 + k0 + c4] = o;
    return;
  }

  // ---- x/e conversion path ----
  const int b  = blockIdx.z;
  const int k0 = blockIdx.x * 64;
  const int f0 = blockIdx.y * 64;
  const int l  = threadIdx.x & 63;
  const int w  = threadIdx.x >> 6;
  const int fi = (l & 15) * 4;
  const int f  = f0 + fi;

#pragma unroll
  for (int it = 0; it < 4; ++it) {
    const int row = w * 16 + it * 4 + (l >> 4);
    const int k = k0 + row;
    float4 v = (f < 512) ? *(const float4*)&x[((long)b * 2048 + k) * 512 + f]
                         : *(const float4*)&e[(long)k * 64 + (f - 512)];
    s16x4 o; o[0] = f2bf(v.x); o[1] = f2bf(v.y); o[2] = f2bf(v.z); o[3] = f2bf(v.w);
    *(s16x4*)&Xe[((long)b * 2048 + k) * 576 + f] = o;
    *(s16x4*)&t[row * LP + fi] = o;
  }
  __syncthreads();
#pragma unroll
  for (int i = 0; i < 2; ++i) {
    const int c  = threadIdx.x + 256 * i;   // 0..511
    const int fr = c >> 3;                  // f row within tile
    const int kc = (c & 7) * 8;             // k chunk
    s16x8 o;
#pragma unroll
    for (int j = 0; j < 8; ++j) o[j] = t[(kc + j) * LP + fr];
    *(s16x8*)&XeT[((long)b * 576 + f0 + fr) * 2048 + k0 + kc] = o;
  }
}

// ---------------------------------------------------------------------------
extern "C" void kernel_launch(void* const* d_in, const int* in_sizes, int n_in,
                              void* d_out, int out_size, void* d_ws, size_t ws_size,
                              hipStream_t stream) {
  const float* x  = (const float*)d_in[0];
  const float* e  = (const float*)d_in[1];
  const float* W0 = (const float*)d_in[2];
  const float* W1 = (const float*)d_in[3];
  const float* W2 = (const float*)d_in[4];
  const float* W3 = (const float*)d_in[5];
  float* out = (float*)d_out;

  const size_t SZ_XeT = (size_t)16 * 576 * 2048 * 2;  // 37,748,736
  const size_t SZ_CT  = (size_t)16 * 512 * 576 * 2;   //  9,437,184
  const size_t SZ_DT  = SZ_CT;
  const size_t SZ_WB  = (size_t)576 * 576 * 2;        //    663,552
  const size_t SZ_XE  = (size_t)16 * 2048 * 576 * 2;  // 37,748,736

  char* p = (char*)d_ws;
  unsigned short* XeT = (unsigned short*)p;  p += SZ_XeT;
  unsigned short* CT  = (unsigned short*)p;  p += SZ_CT;
  unsigned short* DT  = (unsigned short*)p;  p += SZ_DT;
  unsigned short* Wb  = (unsigned short*)p;  p += SZ_WB;
  unsigned short* Xe  = (unsigned short*)p;  p += SZ_XE;
  const size_t base = SZ_XeT + SZ_CT + SZ_DT + SZ_WB + SZ_XE;
  if (ws_size < base) return;  // d_ws is 256MiB; loud failure otherwise

  // One fused pre-pass: x/e -> Xe+XeT (z<16) and W0..W3 -> Wb (z=16,17)
  convert_fused<<<dim3(32, 9, 18), 256, 0, stream>>>(
      x, e, W0, W1, W2, W3, XeT, Xe, Wb);

  // Stage 1: CT[i][j] = sum_k XeT[i][k]*XeT[j][k]   (M=512, N=576, K=2048)
  gemm_nt<64, 96, 8, 6, 0><<<768, 256, 0, stream>>>(
      XeT, (long)576 * 2048, 2048,
      XeT, (long)576 * 2048, 2048,
      CT,  (long)512 * 576, 576, 2048);

  // Stage 2: DT[t][m] = sum_f CT[t][f]*Wb[m][f]     (M=512, N=576, K=576)
  gemm_nt<64, 96, 8, 6, 0><<<768, 256, 0, stream>>>(
      CT, (long)512 * 576, 576,
      Wb, 0L, 576,
      DT, (long)512 * 576, 576, 576);

  // Stage 3: out[n][t] = sum_m Xe[n][m]*DT[t][m]    (M=2048, N=512, K=576)
  gemm_nt<128, 128, 16, 4, 1><<<1024, 256, 0, stream>>>(
      Xe, (long)2048 * 576, 576,
      DT, (long)512 * 576, 576,
      out, (long)2048 * 512, 512, 576);
}